// Round 18
// baseline (418.412 us; speedup 1.0000x reference)
//
#include <hip/hip_runtime.h>
#include <hip/hip_bf16.h>
#include <math.h>
#include <string.h>

#define BB   16
#define NN   128
#define NCC  32
#define HH   256
#define AA   64
#define DEGN 3
#define BNR  (BB*NN)   // 2048 rows

typedef __bf16 bf16x8 __attribute__((ext_vector_type(8)));
typedef float  f32x16 __attribute__((ext_vector_type(16)));

__device__ __forceinline__ unsigned int pk2(float lo, float hi) {
    __hip_bfloat162 h2 = __float22bfloat162_rn(make_float2(lo, hi));
    unsigned int u;
    memcpy(&u, &h2, 4);
    return u;
}
__device__ __forceinline__ float2 unpk(unsigned int u) {
    return make_float2(__uint_as_float(u << 16),
                       __uint_as_float(u & 0xffff0000u));
}
__device__ __forceinline__ unsigned short bfbits(float f) {
    __hip_bfloat16 h = __float2bfloat16(f);
    unsigned short u;
    memcpy(&u, &h, 2);
    return u;
}

// ---------------------------------------------------------------------------
// Kernel 1 (k_head): fused prep (unchanged from round 9).
// ---------------------------------------------------------------------------
__global__ __launch_bounds__(256) void k_head(const float* __restrict__ cond,
                                              const float* __restrict__ cmask,
                                              const float* __restrict__ Wc,
                                              const float* __restrict__ W1,
                                              const float* __restrict__ Wlin,
                                              float* __restrict__ dv,
                                              float* __restrict__ dv_out,
                                              unsigned short* __restrict__ W1t,
                                              unsigned short* __restrict__ Wlt) {
    __shared__ float shm[32 * 33];
    const int bid = blockIdx.x, t = threadIdx.x;

    if (bid < 48) {
        const int d = bid >> 4, b = bid & 15;
        float s = 0.f, ms = 0.f;
        for (int c = 0; c < NCC; ++c) {
            float mk = cmask[b * NCC + c];
            s  += cond[(b * NCC + c) * HH + t] * mk;
            ms += mk;
        }
        shm[t] = s / fmaxf(ms, 1.0f);
        __syncthreads();
        const float* Wd = Wc + (size_t)d * HH * HH;
        float acc = 0.f;
        for (int k = 0; k < HH; ++k) acc += shm[k] * Wd[k * HH + t];
        int idx = (d * BB + b) * HH + t;
        dv[idx]     = acc;
        dv_out[idx] = acc;
    } else if (bid < 240) {
        const int q = bid - 48;
        const int d = q >> 6, r2 = q & 63, tk = r2 >> 3, tn = r2 & 7;
        float (*tile)[33] = (float (*)[33])shm;
        #pragma unroll
        for (int p = 0; p < 4; ++p) {
            int kr = p * 8 + (t >> 5), nr = t & 31;
            tile[kr][nr] = W1[((size_t)d * HH + tk * 32 + kr) * HH + tn * 32 + nr];
        }
        __syncthreads();
        #pragma unroll
        for (int p = 0; p < 4; ++p) {
            int nr = p * 8 + (t >> 5), kr = t & 31;
            W1t[((size_t)d * HH + tn * 32 + nr) * HH + tk * 32 + kr] =
                bfbits(tile[kr][nr]);
        }
    } else {
        const int q = bid - 240;
        const int d = q >> 4, r3 = q & 15, tk = r3 >> 1, ta = r3 & 1;
        float (*tile)[33] = (float (*)[33])shm;
        #pragma unroll
        for (int p = 0; p < 4; ++p) {
            int kr = p * 8 + (t >> 5), ar = t & 31;
            tile[kr][ar] = Wlin[((size_t)d * HH + tk * 32 + kr) * AA + ta * 32 + ar];
        }
        __syncthreads();
        #pragma unroll
        for (int p = 0; p < 4; ++p) {
            int ar = p * 8 + (t >> 5), kr = t & 31;
            Wlt[((size_t)d * AA + ta * 32 + ar) * HH + tk * 32 + kr] =
                bfbits(tile[kr][ar]);
        }
    }
}

// ---------------------------------------------------------------------------
// Kernel 2 (k_mlp): fused encoder+linear via bf16 MFMA (unchanged from r9).
// ---------------------------------------------------------------------------
__global__ __launch_bounds__(256) void k_mlp(const float* __restrict__ x,
                                             const float* __restrict__ xmask,
                                             const float* __restrict__ b1,
                                             const float* __restrict__ blin,
                                             const float* __restrict__ dv,
                                             const unsigned short* __restrict__ W1t,
                                             const unsigned short* __restrict__ Wlt,
                                             float* __restrict__ yv) {
    __shared__ __align__(16) char ldsA[32 * 512];
    __shared__ float ps[2][32][68];

    const int t = threadIdx.x;
    const int d = blockIdx.x >> 6, rt = blockIdx.x & 63;
    const int row0 = rt * 32;
    const int b = row0 >> 7;
    const int lane = t & 63, wid = t >> 6;
    const int rl5 = lane & 31, h2v = lane >> 5;

    #pragma unroll
    for (int it = 0; it < 8; ++it) {
        const int r = wid * 8 + it;
        const float4 v = *(const float4*)&x[(size_t)(row0 + r) * HH + lane * 4];
        uint2 u = make_uint2(pk2(v.x, v.y), pk2(v.z, v.w));
        *(uint2*)(ldsA + r * 512 + ((lane * 8) ^ ((r & 7) << 4))) = u;
    }
    __syncthreads();

    f32x16 acc1[2];
    #pragma unroll
    for (int nt = 0; nt < 2; ++nt)
        #pragma unroll
        for (int e = 0; e < 16; ++e) acc1[nt][e] = 0.f;

    #pragma unroll
    for (int ks = 0; ks < 16; ++ks) {
        bf16x8 af = *(const bf16x8*)(ldsA + rl5 * 512 +
                      ((ks * 32 + h2v * 16) ^ ((rl5 & 7) << 4)));
        #pragma unroll
        for (int nt = 0; nt < 2; ++nt) {
            const int n = wid * 64 + nt * 32 + rl5;
            bf16x8 bf = *(const bf16x8*)(W1t +
                          ((size_t)d * HH + n) * HH + ks * 16 + h2v * 8);
            acc1[nt] = __builtin_amdgcn_mfma_f32_32x32x16_bf16(af, bf, acc1[nt], 0, 0, 0);
        }
    }
    __syncthreads();

    #pragma unroll
    for (int nt = 0; nt < 2; ++nt) {
        const int col = wid * 64 + nt * 32 + rl5;
        const float add = b1[d * HH + col] + dv[(d * BB + b) * HH + col];
        #pragma unroll
        for (int e = 0; e < 16; ++e) {
            const int row = (e & 3) + 8 * (e >> 2) + 4 * h2v;
            float v = acc1[nt][e] + add;
            float u = 0.7978845608028654f * (v + 0.044715f * v * v * v);
            float g = 0.5f * v * (1.0f + tanhf(u));
            *(unsigned short*)(ldsA + row * 512 + ((col * 2) ^ ((row & 7) << 4))) =
                bfbits(g);
        }
    }
    __syncthreads();

    const int qc = wid >> 1, kh = wid & 1;
    f32x16 acc2;
    #pragma unroll
    for (int e = 0; e < 16; ++e) acc2[e] = 0.f;
    #pragma unroll
    for (int ks = 0; ks < 8; ++ks) {
        const int kk = kh * 8 + ks;
        bf16x8 af = *(const bf16x8*)(ldsA + rl5 * 512 +
                      ((kk * 32 + h2v * 16) ^ ((rl5 & 7) << 4)));
        bf16x8 bf = *(const bf16x8*)(Wlt +
                      ((size_t)d * AA + qc * 32 + rl5) * HH + kk * 16 + h2v * 8);
        acc2 = __builtin_amdgcn_mfma_f32_32x32x16_bf16(af, bf, acc2, 0, 0, 0);
    }
    #pragma unroll
    for (int e = 0; e < 16; ++e) {
        const int row = (e & 3) + 8 * (e >> 2) + 4 * h2v;
        ps[kh][row][qc * 32 + rl5] = acc2[e];
    }
    __syncthreads();

    #pragma unroll
    for (int j = 0; j < 8; ++j) {
        const int idx = t * 8 + j;
        const int row = idx >> 6, a = idx & 63;
        float v = ps[0][row][a] + ps[1][row][a] + blin[d * AA + a];
        v *= xmask[row0 + row];
        yv[((size_t)d * BNR + row0 + row) * AA + a] = v;
    }
}

// ---------------------------------------------------------------------------
// Kernel 3 (k_contract): BARRIER-FREE xi loop via in-register A-construction.
// All prior schedules alternated LDS-phase and store-drain because A1/A2
// were constructed into shared LDS (needs bar1/bar2). Now only read-only
// Y0/Y1/Y2 bf16 panels live in LDS (48KB); A1/A2 fragments are built in
// registers at MFMA-read time:
//   af_A1[j] = bf16( s0[k_j]*y1[k_j] + s1[k_j]*y0[k_j] )   (2 panel reads)
//   af_A2[j] = bf16( s2[k_j]*y0[k_j] )                     (1 panel read)
// s-slices are broadcast ds_read_b128 of panel row xr (s0[k] = Y0[xr][k]).
// ONE barrier after the prologue; none afterwards -> waves drift, one
// wave's store drain overlaps other waves' LDS/VALU/MFMA work.
// p/ks/ni accumulation order, swizzle, store geometry = r16. s is now
// bf16-rounded (read from panels) -> absmax shifts slightly.
// ---------------------------------------------------------------------------
__device__ __forceinline__ void lds_fence_barrier() {
    asm volatile("s_waitcnt lgkmcnt(0)" ::: "memory");
    __builtin_amdgcn_s_barrier();
    __builtin_amdgcn_sched_barrier(0);
}

#define LROW 128   // bytes per LDS row (64 bf16)
#define SWZ(r) ((((r) >> 2) & 7) << 4)

__device__ __forceinline__ uint4 ldp(const char* base, int row, int kb) {
    return *(const uint4*)(base + row * LROW + (kb ^ SWZ(row)));
}
__device__ __forceinline__ bf16x8 asbf(uint4 u) {
    union { uint4 a; bf16x8 b; } c; c.a = u; return c.b;
}
// af/bf A1 fragment: per element  s0*y1 + s1*y0  (f32 math, pk2 rounding)
__device__ __forceinline__ bf16x8 mkA1(uint4 y0, uint4 y1,
                                       const float2 s0u[4], const float2 s1u[4]) {
    uint4 r;
    float2 a, b2;
    a = unpk(y0.x); b2 = unpk(y1.x);
    r.x = pk2(s0u[0].x * b2.x + s1u[0].x * a.x, s0u[0].y * b2.y + s1u[0].y * a.y);
    a = unpk(y0.y); b2 = unpk(y1.y);
    r.y = pk2(s0u[1].x * b2.x + s1u[1].x * a.x, s0u[1].y * b2.y + s1u[1].y * a.y);
    a = unpk(y0.z); b2 = unpk(y1.z);
    r.z = pk2(s0u[2].x * b2.x + s1u[2].x * a.x, s0u[2].y * b2.y + s1u[2].y * a.y);
    a = unpk(y0.w); b2 = unpk(y1.w);
    r.w = pk2(s0u[3].x * b2.x + s1u[3].x * a.x, s0u[3].y * b2.y + s1u[3].y * a.y);
    return asbf(r);
}
// A2 fragment: per element  s2*y0
__device__ __forceinline__ bf16x8 mkA2(uint4 y0, const float2 s2u[4]) {
    uint4 r;
    float2 a;
    a = unpk(y0.x); r.x = pk2(s2u[0].x * a.x, s2u[0].y * a.y);
    a = unpk(y0.y); r.y = pk2(s2u[1].x * a.x, s2u[1].y * a.y);
    a = unpk(y0.z); r.z = pk2(s2u[2].x * a.x, s2u[2].y * a.y);
    a = unpk(y0.w); r.w = pk2(s2u[3].x * a.x, s2u[3].y * a.y);
    return asbf(r);
}
#define UNP4(dst, src) { dst[0] = unpk((src).x); dst[1] = unpk((src).y); \
                         dst[2] = unpk((src).z); dst[3] = unpk((src).w); }

__global__ __launch_bounds__(256, 2) void k_contract(const float* __restrict__ yv,
                                                     float* __restrict__ outp) {
    __shared__ __align__(16) char lds[3 * 128 * LROW];   // Y0 | Y1 | Y2, 48KB
    char* Y0b = lds;
    char* Y1b = lds + 1 * 128 * LROW;
    char* Y2b = lds + 2 * 128 * LROW;

    const int t  = threadIdx.x;
    const int b  = blockIdx.x >> 5;
    const int xg = blockIdx.x & 31;

    const float* y0p = yv + (size_t)(0 * BNR + b * NN) * AA;
    const float* y1p = yv + (size_t)(1 * BNR + b * NN) * AA;
    const float* y2p = yv + (size_t)(2 * BNR + b * NN) * AA;

    const int lane = t & 63;
    const int wid  = t >> 6;
    const int li   = lane & 31;
    const int rh   = lane >> 5;
    const int rl5  = lane & 31, h2v = lane >> 5;
    const int wy   = wid * 32;            // this wave's output row stripe
    const int arow = wy + rl5;
    const float inv = 1.0f / 4096.0f;

    // ---- prologue: stage Y0, Y1, Y2 as bf16 panels (once per block) ----
    #pragma unroll
    for (int it = 0; it < 16; ++it) {
        const int r   = wid * 32 + it * 2 + rh;
        const int off = r * LROW + ((4 * li) ^ SWZ(r));
        const float2 v0 = *(const float2*)&y0p[r * AA + 2 * li];
        const float2 v1 = *(const float2*)&y1p[r * AA + 2 * li];
        const float2 v2 = *(const float2*)&y2p[r * AA + 2 * li];
        *(unsigned int*)(Y0b + off) = pk2(v0.x, v0.y);
        *(unsigned int*)(Y1b + off) = pk2(v1.x, v1.y);
        *(unsigned int*)(Y2b + off) = pk2(v2.x, v2.y);
    }
    lds_fence_barrier();   // the ONLY barrier: Y panels visible to all waves

    #pragma unroll
    for (int xi = 0; xi < 4; ++xi) {
        const int xr = xg * 4 + xi;

        // ---- s-slices: broadcast reads of panel row xr (s0=Y0[xr], etc.) ----
        uint4 s0f[4], s1f[4], s2f[4];
        #pragma unroll
        for (int ks = 0; ks < 4; ++ks) {
            const int kb = ks * 32 + h2v * 16;
            s0f[ks] = ldp(Y0b, xr, kb);
            s1f[ks] = ldp(Y1b, xr, kb);
            s2f[ks] = ldp(Y2b, xr, kb);
        }

        f32x16 acc[4];
        #pragma unroll
        for (int ni = 0; ni < 4; ++ni)
            #pragma unroll
            for (int e = 0; e < 16; ++e) acc[ni][e] = 0.f;

        // ---- p0: af = A1 (own row, in-reg), bf = B1 = Y2 (direct) ----
        #pragma unroll
        for (int ks = 0; ks < 4; ++ks) {
            const int kb = ks * 32 + h2v * 16;
            float2 s0u[4], s1u[4];
            UNP4(s0u, s0f[ks]); UNP4(s1u, s1f[ks]);
            bf16x8 af = mkA1(ldp(Y0b, arow, kb), ldp(Y1b, arow, kb), s0u, s1u);
            #pragma unroll
            for (int ni = 0; ni < 4; ++ni) {
                bf16x8 bf = asbf(ldp(Y2b, 4 * rl5 + ni, kb));
                acc[ni] = __builtin_amdgcn_mfma_f32_32x32x16_bf16(af, bf, acc[ni], 0, 0, 0);
            }
        }
        // ---- p1: af = B1 = Y2 (own row), bf = A1 (in-reg) ----
        #pragma unroll
        for (int ks = 0; ks < 4; ++ks) {
            const int kb = ks * 32 + h2v * 16;
            float2 s0u[4], s1u[4];
            UNP4(s0u, s0f[ks]); UNP4(s1u, s1f[ks]);
            bf16x8 af = asbf(ldp(Y2b, arow, kb));
            #pragma unroll
            for (int ni = 0; ni < 4; ++ni) {
                const int brow = 4 * rl5 + ni;
                bf16x8 bf = mkA1(ldp(Y0b, brow, kb), ldp(Y1b, brow, kb), s0u, s1u);
                acc[ni] = __builtin_amdgcn_mfma_f32_32x32x16_bf16(af, bf, acc[ni], 0, 0, 0);
            }
        }
        // ---- p2: af = A2 (own row, in-reg), bf = B2 = Y1 (direct) ----
        #pragma unroll
        for (int ks = 0; ks < 4; ++ks) {
            const int kb = ks * 32 + h2v * 16;
            float2 s2u[4];
            UNP4(s2u, s2f[ks]);
            bf16x8 af = mkA2(ldp(Y0b, arow, kb), s2u);
            #pragma unroll
            for (int ni = 0; ni < 4; ++ni) {
                bf16x8 bf = asbf(ldp(Y1b, 4 * rl5 + ni, kb));
                acc[ni] = __builtin_amdgcn_mfma_f32_32x32x16_bf16(af, bf, acc[ni], 0, 0, 0);
            }
        }
        // ---- p3: af = B2 = Y1 (own row), bf = A2 (in-reg) ----
        #pragma unroll
        for (int ks = 0; ks < 4; ++ks) {
            const int kb = ks * 32 + h2v * 16;
            float2 s2u[4];
            UNP4(s2u, s2f[ks]);
            bf16x8 af = asbf(ldp(Y1b, arow, kb));
            #pragma unroll
            for (int ni = 0; ni < 4; ++ni) {
                bf16x8 bf = mkA2(ldp(Y0b, 4 * rl5 + ni, kb), s2u);
                acc[ni] = __builtin_amdgcn_mfma_f32_32x32x16_bf16(af, bf, acc[ni], 0, 0, 0);
            }
        }

        // ---- epilogue: direct full-row stores (r16 geometry, no LDS) ----
        float* osl = outp + ((size_t)(b * NN + xr)) * (NN * NN);
        #pragma unroll
        for (int e = 0; e < 16; ++e) {
            const int rowf = wy + (e & 3) + 8 * (e >> 2) + 4 * h2v;
            float4 v = make_float4(acc[0][e] * inv, acc[1][e] * inv,
                                   acc[2][e] * inv, acc[3][e] * inv);
            *(float4*)&osl[(size_t)rowf * NN + 4 * rl5] = v;
        }
        // no barrier: next xi reads only the read-only Y panels
    }
}

// ---------------------------------------------------------------------------
extern "C" void kernel_launch(void* const* d_in, const int* in_sizes, int n_in,
                              void* d_out, int out_size, void* d_ws, size_t ws_size,
                              hipStream_t stream) {
    const float* x     = (const float*)d_in[0];
    const float* xmask = (const float*)d_in[1];
    const float* cond  = (const float*)d_in[2];
    const float* cmask = (const float*)d_in[3];
    const float* W1    = (const float*)d_in[4];
    const float* b1    = (const float*)d_in[5];
    const float* Wc    = (const float*)d_in[6];
    const float* Wlin  = (const float*)d_in[7];
    const float* blin  = (const float*)d_in[8];

    float* out = (float*)d_out;
    float* ws  = (float*)d_ws;

    float* dv  = ws;                               // 3*16*256 f
    float* yv  = ws + 12288;                       // 3*2048*64 f
    unsigned short* W1t = (unsigned short*)((char*)d_ws + (size_t)(12288 + 393216) * 4);
    unsigned short* Wlt = W1t + (size_t)DEGN * HH * HH;
    float* dv_out = out + (size_t)BB * NN * NN * NN;

    k_head    <<<dim3(288), dim3(256), 0, stream>>>(cond, cmask, Wc, W1, Wlin,
                                                    dv, dv_out, W1t, Wlt);
    k_mlp     <<<dim3(DEGN * 64), dim3(256), 0, stream>>>(x, xmask, b1, blin, dv,
                                                          W1t, Wlt, yv);
    k_contract<<<dim3(BB * NN / 4), dim3(256), 0, stream>>>(yv, out);
}

// Round 19
// 186.253 us; speedup vs baseline: 2.2465x; 2.2465x over previous
//
#include <hip/hip_runtime.h>
#include <hip/hip_bf16.h>
#include <math.h>
#include <string.h>

#define BB   16
#define NN   128
#define NCC  32
#define HH   256
#define AA   64
#define DEGN 3
#define BNR  (BB*NN)   // 2048 rows

typedef __bf16 bf16x8 __attribute__((ext_vector_type(8)));
typedef float  f32x16 __attribute__((ext_vector_type(16)));

__device__ __forceinline__ unsigned int pk2(float lo, float hi) {
    __hip_bfloat162 h2 = __float22bfloat162_rn(make_float2(lo, hi));
    unsigned int u;
    memcpy(&u, &h2, 4);
    return u;
}
__device__ __forceinline__ float2 unpk(unsigned int u) {
    return make_float2(__uint_as_float(u << 16),
                       __uint_as_float(u & 0xffff0000u));
}
__device__ __forceinline__ unsigned short bfbits(float f) {
    __hip_bfloat16 h = __float2bfloat16(f);
    unsigned short u;
    memcpy(&u, &h, 2);
    return u;
}

// ---------------------------------------------------------------------------
// Kernel 1 (k_head): fused prep (unchanged from round 9).
// ---------------------------------------------------------------------------
__global__ __launch_bounds__(256) void k_head(const float* __restrict__ cond,
                                              const float* __restrict__ cmask,
                                              const float* __restrict__ Wc,
                                              const float* __restrict__ W1,
                                              const float* __restrict__ Wlin,
                                              float* __restrict__ dv,
                                              float* __restrict__ dv_out,
                                              unsigned short* __restrict__ W1t,
                                              unsigned short* __restrict__ Wlt) {
    __shared__ float shm[32 * 33];
    const int bid = blockIdx.x, t = threadIdx.x;

    if (bid < 48) {
        const int d = bid >> 4, b = bid & 15;
        float s = 0.f, ms = 0.f;
        for (int c = 0; c < NCC; ++c) {
            float mk = cmask[b * NCC + c];
            s  += cond[(b * NCC + c) * HH + t] * mk;
            ms += mk;
        }
        shm[t] = s / fmaxf(ms, 1.0f);
        __syncthreads();
        const float* Wd = Wc + (size_t)d * HH * HH;
        float acc = 0.f;
        for (int k = 0; k < HH; ++k) acc += shm[k] * Wd[k * HH + t];
        int idx = (d * BB + b) * HH + t;
        dv[idx]     = acc;
        dv_out[idx] = acc;
    } else if (bid < 240) {
        const int q = bid - 48;
        const int d = q >> 6, r2 = q & 63, tk = r2 >> 3, tn = r2 & 7;
        float (*tile)[33] = (float (*)[33])shm;
        #pragma unroll
        for (int p = 0; p < 4; ++p) {
            int kr = p * 8 + (t >> 5), nr = t & 31;
            tile[kr][nr] = W1[((size_t)d * HH + tk * 32 + kr) * HH + tn * 32 + nr];
        }
        __syncthreads();
        #pragma unroll
        for (int p = 0; p < 4; ++p) {
            int nr = p * 8 + (t >> 5), kr = t & 31;
            W1t[((size_t)d * HH + tn * 32 + nr) * HH + tk * 32 + kr] =
                bfbits(tile[kr][nr]);
        }
    } else {
        const int q = bid - 240;
        const int d = q >> 4, r3 = q & 15, tk = r3 >> 1, ta = r3 & 1;
        float (*tile)[33] = (float (*)[33])shm;
        #pragma unroll
        for (int p = 0; p < 4; ++p) {
            int kr = p * 8 + (t >> 5), ar = t & 31;
            tile[kr][ar] = Wlin[((size_t)d * HH + tk * 32 + kr) * AA + ta * 32 + ar];
        }
        __syncthreads();
        #pragma unroll
        for (int p = 0; p < 4; ++p) {
            int ar = p * 8 + (t >> 5), kr = t & 31;
            Wlt[((size_t)d * AA + ta * 32 + ar) * HH + tk * 32 + kr] =
                bfbits(tile[kr][ar]);
        }
    }
}

// ---------------------------------------------------------------------------
// Kernel 2 (k_mlp): fused encoder+linear via bf16 MFMA (unchanged from r9).
// ---------------------------------------------------------------------------
__global__ __launch_bounds__(256) void k_mlp(const float* __restrict__ x,
                                             const float* __restrict__ xmask,
                                             const float* __restrict__ b1,
                                             const float* __restrict__ blin,
                                             const float* __restrict__ dv,
                                             const unsigned short* __restrict__ W1t,
                                             const unsigned short* __restrict__ Wlt,
                                             float* __restrict__ yv) {
    __shared__ __align__(16) char ldsA[32 * 512];
    __shared__ float ps[2][32][68];

    const int t = threadIdx.x;
    const int d = blockIdx.x >> 6, rt = blockIdx.x & 63;
    const int row0 = rt * 32;
    const int b = row0 >> 7;
    const int lane = t & 63, wid = t >> 6;
    const int rl5 = lane & 31, h2v = lane >> 5;

    #pragma unroll
    for (int it = 0; it < 8; ++it) {
        const int r = wid * 8 + it;
        const float4 v = *(const float4*)&x[(size_t)(row0 + r) * HH + lane * 4];
        uint2 u = make_uint2(pk2(v.x, v.y), pk2(v.z, v.w));
        *(uint2*)(ldsA + r * 512 + ((lane * 8) ^ ((r & 7) << 4))) = u;
    }
    __syncthreads();

    f32x16 acc1[2];
    #pragma unroll
    for (int nt = 0; nt < 2; ++nt)
        #pragma unroll
        for (int e = 0; e < 16; ++e) acc1[nt][e] = 0.f;

    #pragma unroll
    for (int ks = 0; ks < 16; ++ks) {
        bf16x8 af = *(const bf16x8*)(ldsA + rl5 * 512 +
                      ((ks * 32 + h2v * 16) ^ ((rl5 & 7) << 4)));
        #pragma unroll
        for (int nt = 0; nt < 2; ++nt) {
            const int n = wid * 64 + nt * 32 + rl5;
            bf16x8 bf = *(const bf16x8*)(W1t +
                          ((size_t)d * HH + n) * HH + ks * 16 + h2v * 8);
            acc1[nt] = __builtin_amdgcn_mfma_f32_32x32x16_bf16(af, bf, acc1[nt], 0, 0, 0);
        }
    }
    __syncthreads();

    #pragma unroll
    for (int nt = 0; nt < 2; ++nt) {
        const int col = wid * 64 + nt * 32 + rl5;
        const float add = b1[d * HH + col] + dv[(d * BB + b) * HH + col];
        #pragma unroll
        for (int e = 0; e < 16; ++e) {
            const int row = (e & 3) + 8 * (e >> 2) + 4 * h2v;
            float v = acc1[nt][e] + add;
            float u = 0.7978845608028654f * (v + 0.044715f * v * v * v);
            float g = 0.5f * v * (1.0f + tanhf(u));
            *(unsigned short*)(ldsA + row * 512 + ((col * 2) ^ ((row & 7) << 4))) =
                bfbits(g);
        }
    }
    __syncthreads();

    const int qc = wid >> 1, kh = wid & 1;
    f32x16 acc2;
    #pragma unroll
    for (int e = 0; e < 16; ++e) acc2[e] = 0.f;
    #pragma unroll
    for (int ks = 0; ks < 8; ++ks) {
        const int kk = kh * 8 + ks;
        bf16x8 af = *(const bf16x8*)(ldsA + rl5 * 512 +
                      ((kk * 32 + h2v * 16) ^ ((rl5 & 7) << 4)));
        bf16x8 bf = *(const bf16x8*)(Wlt +
                      ((size_t)d * AA + qc * 32 + rl5) * HH + kk * 16 + h2v * 8);
        acc2 = __builtin_amdgcn_mfma_f32_32x32x16_bf16(af, bf, acc2, 0, 0, 0);
    }
    #pragma unroll
    for (int e = 0; e < 16; ++e) {
        const int row = (e & 3) + 8 * (e >> 2) + 4 * h2v;
        ps[kh][row][qc * 32 + rl5] = acc2[e];
    }
    __syncthreads();

    #pragma unroll
    for (int j = 0; j < 8; ++j) {
        const int idx = t * 8 + j;
        const int row = idx >> 6, a = idx & 63;
        float v = ps[0][row][a] + ps[1][row][a] + blin[d * AA + a];
        v *= xmask[row0 + row];
        yv[((size_t)d * BNR + row0 + row) * AA + a] = v;
    }
}

// ---------------------------------------------------------------------------
// Kernel 3 (k_contract): barrier-free xi loop, diagonal decomposition with
// af-SIDE-ONLY in-register scaling (r18 spill fix: never construct bf,
// never cache s-frags — max ~3 live uint4).
//   out*4096 = (Y1 D0 + Y0 D1) Y2^T            [T12 — same mkA1 expression]
//            +  (Y2 D0) Y1^T + (Y2 D1) Y0^T    [T3, T4]
//            +  (Y0 D2) Y1^T + (Y1 D2) Y0^T    [T5, T6]
// where Dk = diag(Yk[x,:]); af = own-row fragment scaled elementwise by s
// (s read as broadcast ds_read_b128 of panel row x), bf = DIRECT read-only
// panel read. 5 MFMA passes x 4 ks x 4 ni = 80 MFMA/xi. LDS = Y0|Y1|Y2
// bf16 panels only (48KB, read-only) -> ONE barrier total; waves drift, so
// one wave's store drain overlaps other waves' LDS/MFMA (the phase-locking
// fix r17/r18 contaminated). Store geometry = r16 (full-row float4,
// permuted bf rows 4*rl5+ni). VGPR ~110. #pragma unroll 1 on xi loop.
// ---------------------------------------------------------------------------
__device__ __forceinline__ void lds_fence_barrier() {
    asm volatile("s_waitcnt lgkmcnt(0)" ::: "memory");
    __builtin_amdgcn_s_barrier();
    __builtin_amdgcn_sched_barrier(0);
}

#define LROW 128   // bytes per LDS row (64 bf16)
#define SWZ(r) ((((r) >> 2) & 7) << 4)

__device__ __forceinline__ uint4 ldp(const char* base, int row, int kb) {
    return *(const uint4*)(base + row * LROW + (kb ^ SWZ(row)));
}
__device__ __forceinline__ bf16x8 asbf(uint4 u) {
    union { uint4 a; bf16x8 b; } c; c.a = u; return c.b;
}
// af = bf16( s .* y )  elementwise (8 lanes of bf16 pairs)
__device__ __forceinline__ bf16x8 mkScaled(uint4 y, uint4 s) {
    uint4 r;
    float2 a, w;
    a = unpk(y.x); w = unpk(s.x); r.x = pk2(w.x * a.x, w.y * a.y);
    a = unpk(y.y); w = unpk(s.y); r.y = pk2(w.x * a.x, w.y * a.y);
    a = unpk(y.z); w = unpk(s.z); r.z = pk2(w.x * a.x, w.y * a.y);
    a = unpk(y.w); w = unpk(s.w); r.w = pk2(w.x * a.x, w.y * a.y);
    return asbf(r);
}
// af = bf16( s0 .* y1 + s1 .* y0 )  (r16's A1 expression)
__device__ __forceinline__ bf16x8 mkA1(uint4 y0, uint4 y1, uint4 s0, uint4 s1) {
    uint4 r;
    float2 a, b2, w0, w1;
    a = unpk(y0.x); b2 = unpk(y1.x); w0 = unpk(s0.x); w1 = unpk(s1.x);
    r.x = pk2(w0.x * b2.x + w1.x * a.x, w0.y * b2.y + w1.y * a.y);
    a = unpk(y0.y); b2 = unpk(y1.y); w0 = unpk(s0.y); w1 = unpk(s1.y);
    r.y = pk2(w0.x * b2.x + w1.x * a.x, w0.y * b2.y + w1.y * a.y);
    a = unpk(y0.z); b2 = unpk(y1.z); w0 = unpk(s0.z); w1 = unpk(s1.z);
    r.z = pk2(w0.x * b2.x + w1.x * a.x, w0.y * b2.y + w1.y * a.y);
    a = unpk(y0.w); b2 = unpk(y1.w); w0 = unpk(s0.w); w1 = unpk(s1.w);
    r.w = pk2(w0.x * b2.x + w1.x * a.x, w0.y * b2.y + w1.y * a.y);
    return asbf(r);
}

__global__ __launch_bounds__(256, 2) void k_contract(const float* __restrict__ yv,
                                                     float* __restrict__ outp) {
    __shared__ __align__(16) char lds[3 * 128 * LROW];   // Y0 | Y1 | Y2, 48KB
    char* Y0b = lds;
    char* Y1b = lds + 1 * 128 * LROW;
    char* Y2b = lds + 2 * 128 * LROW;

    const int t  = threadIdx.x;
    const int b  = blockIdx.x >> 5;
    const int xg = blockIdx.x & 31;

    const float* y0p = yv + (size_t)(0 * BNR + b * NN) * AA;
    const float* y1p = yv + (size_t)(1 * BNR + b * NN) * AA;
    const float* y2p = yv + (size_t)(2 * BNR + b * NN) * AA;

    const int lane = t & 63;
    const int wid  = t >> 6;
    const int li   = lane & 31;
    const int rh   = lane >> 5;
    const int rl5  = lane & 31, h2v = lane >> 5;
    const int wy   = wid * 32;            // this wave's output row stripe
    const int arow = wy + rl5;
    const float inv = 1.0f / 4096.0f;

    // ---- prologue: stage Y0, Y1, Y2 as bf16 panels (once per block) ----
    #pragma unroll
    for (int it = 0; it < 16; ++it) {
        const int r   = wid * 32 + it * 2 + rh;
        const int off = r * LROW + ((4 * li) ^ SWZ(r));
        const float2 v0 = *(const float2*)&y0p[r * AA + 2 * li];
        const float2 v1 = *(const float2*)&y1p[r * AA + 2 * li];
        const float2 v2 = *(const float2*)&y2p[r * AA + 2 * li];
        *(unsigned int*)(Y0b + off) = pk2(v0.x, v0.y);
        *(unsigned int*)(Y1b + off) = pk2(v1.x, v1.y);
        *(unsigned int*)(Y2b + off) = pk2(v2.x, v2.y);
    }
    lds_fence_barrier();   // the ONLY barrier: Y panels visible to all waves

    #pragma unroll 1
    for (int xi = 0; xi < 4; ++xi) {
        const int xr = xg * 4 + xi;

        f32x16 acc[4];
        #pragma unroll
        for (int ni = 0; ni < 4; ++ni)
            #pragma unroll
            for (int e = 0; e < 16; ++e) acc[ni][e] = 0.f;

        // ---- T12: af = bf16(s0*y1 + s1*y0) own-row; bf = Y2 ----
        #pragma unroll
        for (int ks = 0; ks < 4; ++ks) {
            const int kb = ks * 32 + h2v * 16;
            bf16x8 af = mkA1(ldp(Y0b, arow, kb), ldp(Y1b, arow, kb),
                             ldp(Y0b, xr, kb),   ldp(Y1b, xr, kb));
            #pragma unroll
            for (int ni = 0; ni < 4; ++ni) {
                bf16x8 bf = asbf(ldp(Y2b, 4 * rl5 + ni, kb));
                acc[ni] = __builtin_amdgcn_mfma_f32_32x32x16_bf16(af, bf, acc[ni], 0, 0, 0);
            }
        }
        // ---- T3: af = (Y2 . D0) own-row; bf = Y1 ----
        #pragma unroll
        for (int ks = 0; ks < 4; ++ks) {
            const int kb = ks * 32 + h2v * 16;
            bf16x8 af = mkScaled(ldp(Y2b, arow, kb), ldp(Y0b, xr, kb));
            #pragma unroll
            for (int ni = 0; ni < 4; ++ni) {
                bf16x8 bf = asbf(ldp(Y1b, 4 * rl5 + ni, kb));
                acc[ni] = __builtin_amdgcn_mfma_f32_32x32x16_bf16(af, bf, acc[ni], 0, 0, 0);
            }
        }
        // ---- T4: af = (Y2 . D1) own-row; bf = Y0 ----
        #pragma unroll
        for (int ks = 0; ks < 4; ++ks) {
            const int kb = ks * 32 + h2v * 16;
            bf16x8 af = mkScaled(ldp(Y2b, arow, kb), ldp(Y1b, xr, kb));
            #pragma unroll
            for (int ni = 0; ni < 4; ++ni) {
                bf16x8 bf = asbf(ldp(Y0b, 4 * rl5 + ni, kb));
                acc[ni] = __builtin_amdgcn_mfma_f32_32x32x16_bf16(af, bf, acc[ni], 0, 0, 0);
            }
        }
        // ---- T5: af = (Y0 . D2) own-row; bf = Y1 ----
        #pragma unroll
        for (int ks = 0; ks < 4; ++ks) {
            const int kb = ks * 32 + h2v * 16;
            bf16x8 af = mkScaled(ldp(Y0b, arow, kb), ldp(Y2b, xr, kb));
            #pragma unroll
            for (int ni = 0; ni < 4; ++ni) {
                bf16x8 bf = asbf(ldp(Y1b, 4 * rl5 + ni, kb));
                acc[ni] = __builtin_amdgcn_mfma_f32_32x32x16_bf16(af, bf, acc[ni], 0, 0, 0);
            }
        }
        // ---- T6: af = (Y1 . D2) own-row; bf = Y0 ----
        #pragma unroll
        for (int ks = 0; ks < 4; ++ks) {
            const int kb = ks * 32 + h2v * 16;
            bf16x8 af = mkScaled(ldp(Y1b, arow, kb), ldp(Y2b, xr, kb));
            #pragma unroll
            for (int ni = 0; ni < 4; ++ni) {
                bf16x8 bf = asbf(ldp(Y0b, 4 * rl5 + ni, kb));
                acc[ni] = __builtin_amdgcn_mfma_f32_32x32x16_bf16(af, bf, acc[ni], 0, 0, 0);
            }
        }

        // ---- epilogue: direct full-row stores (r16 geometry, no LDS) ----
        float* osl = outp + ((size_t)(b * NN + xr)) * (NN * NN);
        #pragma unroll
        for (int e = 0; e < 16; ++e) {
            const int rowf = wy + (e & 3) + 8 * (e >> 2) + 4 * h2v;
            float4 v = make_float4(acc[0][e] * inv, acc[1][e] * inv,
                                   acc[2][e] * inv, acc[3][e] * inv);
            *(float4*)&osl[(size_t)rowf * NN + 4 * rl5] = v;
        }
        // no barrier: next xi reads only the read-only Y panels
    }
}

// ---------------------------------------------------------------------------
extern "C" void kernel_launch(void* const* d_in, const int* in_sizes, int n_in,
                              void* d_out, int out_size, void* d_ws, size_t ws_size,
                              hipStream_t stream) {
    const float* x     = (const float*)d_in[0];
    const float* xmask = (const float*)d_in[1];
    const float* cond  = (const float*)d_in[2];
    const float* cmask = (const float*)d_in[3];
    const float* W1    = (const float*)d_in[4];
    const float* b1    = (const float*)d_in[5];
    const float* Wc    = (const float*)d_in[6];
    const float* Wlin  = (const float*)d_in[7];
    const float* blin  = (const float*)d_in[8];

    float* out = (float*)d_out;
    float* ws  = (float*)d_ws;

    float* dv  = ws;                               // 3*16*256 f
    float* yv  = ws + 12288;                       // 3*2048*64 f
    unsigned short* W1t = (unsigned short*)((char*)d_ws + (size_t)(12288 + 393216) * 4);
    unsigned short* Wlt = W1t + (size_t)DEGN * HH * HH;
    float* dv_out = out + (size_t)BB * NN * NN * NN;

    k_head    <<<dim3(288), dim3(256), 0, stream>>>(cond, cmask, Wc, W1, Wlin,
                                                    dv, dv_out, W1t, Wlt);
    k_mlp     <<<dim3(DEGN * 64), dim3(256), 0, stream>>>(x, xmask, b1, blin, dv,
                                                          W1t, Wlt, yv);
    k_contract<<<dim3(BB * NN / 4), dim3(256), 0, stream>>>(yv, out);
}

// Round 20
// 55.293 us; speedup vs baseline: 7.5672x; 3.3685x over previous
//
#include <hip/hip_runtime.h>
#include <hip/hip_bf16.h>
#include <math.h>
#include <string.h>

#define BB   16
#define NN   128
#define NCC  32
#define HH   256
#define AA   64
#define DEGN 3
#define BNR  (BB*NN)   // 2048 rows

typedef __bf16 bf16x8 __attribute__((ext_vector_type(8)));
typedef float  f32x16 __attribute__((ext_vector_type(16)));

__device__ __forceinline__ unsigned int pk2(float lo, float hi) {
    __hip_bfloat162 h2 = __float22bfloat162_rn(make_float2(lo, hi));
    unsigned int u;
    memcpy(&u, &h2, 4);
    return u;
}
__device__ __forceinline__ float2 unpk(unsigned int u) {
    return make_float2(__uint_as_float(u << 16),
                       __uint_as_float(u & 0xffff0000u));
}
__device__ __forceinline__ unsigned short bfbits(float f) {
    __hip_bfloat16 h = __float2bfloat16(f);
    unsigned short u;
    memcpy(&u, &h, 2);
    return u;
}

// ---------------------------------------------------------------------------
// Kernel 1 (k_head): fused prep (unchanged from round 9).
// ---------------------------------------------------------------------------
__global__ __launch_bounds__(256) void k_head(const float* __restrict__ cond,
                                              const float* __restrict__ cmask,
                                              const float* __restrict__ Wc,
                                              const float* __restrict__ W1,
                                              const float* __restrict__ Wlin,
                                              float* __restrict__ dv,
                                              float* __restrict__ dv_out,
                                              unsigned short* __restrict__ W1t,
                                              unsigned short* __restrict__ Wlt) {
    __shared__ float shm[32 * 33];
    const int bid = blockIdx.x, t = threadIdx.x;

    if (bid < 48) {
        const int d = bid >> 4, b = bid & 15;
        float s = 0.f, ms = 0.f;
        for (int c = 0; c < NCC; ++c) {
            float mk = cmask[b * NCC + c];
            s  += cond[(b * NCC + c) * HH + t] * mk;
            ms += mk;
        }
        shm[t] = s / fmaxf(ms, 1.0f);
        __syncthreads();
        const float* Wd = Wc + (size_t)d * HH * HH;
        float acc = 0.f;
        for (int k = 0; k < HH; ++k) acc += shm[k] * Wd[k * HH + t];
        int idx = (d * BB + b) * HH + t;
        dv[idx]     = acc;
        dv_out[idx] = acc;
    } else if (bid < 240) {
        const int q = bid - 48;
        const int d = q >> 6, r2 = q & 63, tk = r2 >> 3, tn = r2 & 7;
        float (*tile)[33] = (float (*)[33])shm;
        #pragma unroll
        for (int p = 0; p < 4; ++p) {
            int kr = p * 8 + (t >> 5), nr = t & 31;
            tile[kr][nr] = W1[((size_t)d * HH + tk * 32 + kr) * HH + tn * 32 + nr];
        }
        __syncthreads();
        #pragma unroll
        for (int p = 0; p < 4; ++p) {
            int nr = p * 8 + (t >> 5), kr = t & 31;
            W1t[((size_t)d * HH + tn * 32 + nr) * HH + tk * 32 + kr] =
                bfbits(tile[kr][nr]);
        }
    } else {
        const int q = bid - 240;
        const int d = q >> 4, r3 = q & 15, tk = r3 >> 1, ta = r3 & 1;
        float (*tile)[33] = (float (*)[33])shm;
        #pragma unroll
        for (int p = 0; p < 4; ++p) {
            int kr = p * 8 + (t >> 5), ar = t & 31;
            tile[kr][ar] = Wlin[((size_t)d * HH + tk * 32 + kr) * AA + ta * 32 + ar];
        }
        __syncthreads();
        #pragma unroll
        for (int p = 0; p < 4; ++p) {
            int ar = p * 8 + (t >> 5), kr = t & 31;
            Wlt[((size_t)d * AA + ta * 32 + ar) * HH + tk * 32 + kr] =
                bfbits(tile[kr][ar]);
        }
    }
}

// ---------------------------------------------------------------------------
// Kernel 2 (k_mlp): fused encoder+linear via bf16 MFMA (unchanged from r9).
// ---------------------------------------------------------------------------
__global__ __launch_bounds__(256) void k_mlp(const float* __restrict__ x,
                                             const float* __restrict__ xmask,
                                             const float* __restrict__ b1,
                                             const float* __restrict__ blin,
                                             const float* __restrict__ dv,
                                             const unsigned short* __restrict__ W1t,
                                             const unsigned short* __restrict__ Wlt,
                                             float* __restrict__ yv) {
    __shared__ __align__(16) char ldsA[32 * 512];
    __shared__ float ps[2][32][68];

    const int t = threadIdx.x;
    const int d = blockIdx.x >> 6, rt = blockIdx.x & 63;
    const int row0 = rt * 32;
    const int b = row0 >> 7;
    const int lane = t & 63, wid = t >> 6;
    const int rl5 = lane & 31, h2v = lane >> 5;

    #pragma unroll
    for (int it = 0; it < 8; ++it) {
        const int r = wid * 8 + it;
        const float4 v = *(const float4*)&x[(size_t)(row0 + r) * HH + lane * 4];
        uint2 u = make_uint2(pk2(v.x, v.y), pk2(v.z, v.w));
        *(uint2*)(ldsA + r * 512 + ((lane * 8) ^ ((r & 7) << 4))) = u;
    }
    __syncthreads();

    f32x16 acc1[2];
    #pragma unroll
    for (int nt = 0; nt < 2; ++nt)
        #pragma unroll
        for (int e = 0; e < 16; ++e) acc1[nt][e] = 0.f;

    #pragma unroll
    for (int ks = 0; ks < 16; ++ks) {
        bf16x8 af = *(const bf16x8*)(ldsA + rl5 * 512 +
                      ((ks * 32 + h2v * 16) ^ ((rl5 & 7) << 4)));
        #pragma unroll
        for (int nt = 0; nt < 2; ++nt) {
            const int n = wid * 64 + nt * 32 + rl5;
            bf16x8 bf = *(const bf16x8*)(W1t +
                          ((size_t)d * HH + n) * HH + ks * 16 + h2v * 8);
            acc1[nt] = __builtin_amdgcn_mfma_f32_32x32x16_bf16(af, bf, acc1[nt], 0, 0, 0);
        }
    }
    __syncthreads();

    #pragma unroll
    for (int nt = 0; nt < 2; ++nt) {
        const int col = wid * 64 + nt * 32 + rl5;
        const float add = b1[d * HH + col] + dv[(d * BB + b) * HH + col];
        #pragma unroll
        for (int e = 0; e < 16; ++e) {
            const int row = (e & 3) + 8 * (e >> 2) + 4 * h2v;
            float v = acc1[nt][e] + add;
            float u = 0.7978845608028654f * (v + 0.044715f * v * v * v);
            float g = 0.5f * v * (1.0f + tanhf(u));
            *(unsigned short*)(ldsA + row * 512 + ((col * 2) ^ ((row & 7) << 4))) =
                bfbits(g);
        }
    }
    __syncthreads();

    const int qc = wid >> 1, kh = wid & 1;
    f32x16 acc2;
    #pragma unroll
    for (int e = 0; e < 16; ++e) acc2[e] = 0.f;
    #pragma unroll
    for (int ks = 0; ks < 8; ++ks) {
        const int kk = kh * 8 + ks;
        bf16x8 af = *(const bf16x8*)(ldsA + rl5 * 512 +
                      ((kk * 32 + h2v * 16) ^ ((rl5 & 7) << 4)));
        bf16x8 bf = *(const bf16x8*)(Wlt +
                      ((size_t)d * AA + qc * 32 + rl5) * HH + kk * 16 + h2v * 8);
        acc2 = __builtin_amdgcn_mfma_f32_32x32x16_bf16(af, bf, acc2, 0, 0, 0);
    }
    #pragma unroll
    for (int e = 0; e < 16; ++e) {
        const int row = (e & 3) + 8 * (e >> 2) + 4 * h2v;
        ps[kh][row][qc * 32 + rl5] = acc2[e];
    }
    __syncthreads();

    #pragma unroll
    for (int j = 0; j < 8; ++j) {
        const int idx = t * 8 + j;
        const int row = idx >> 6, a = idx & 63;
        float v = ps[0][row][a] + ps[1][row][a] + blin[d * AA + a];
        v *= xmask[row0 + row];
        yv[((size_t)d * BNR + row0 + row) * AA + a] = v;
    }
}

// ---------------------------------------------------------------------------
// Kernel 3 (k_contract): r16 optimum, verbatim (best: 55.31 us total).
// out*4096 = A1 B1^T + B1 A1^T + A2 B2^T + B2 A2^T per (b,x).
// Zero global loads in the xi loop; A1/A2 constructed in LDS from bf16
// Y panels; bf read from LDS row 4*rl5+ni so lane rl5 holds problem cols
// {4rl5..4rl5+3} in acc[0..3][e] -> direct full-row float4 stores, no
// epilogue LDS bounce. SWZ ((r>>2)&7)<<4. 80KB LDS, 2 blocks/CU, VGPR 100.
// ---------------------------------------------------------------------------
__device__ __forceinline__ void lds_fence_barrier() {
    asm volatile("s_waitcnt lgkmcnt(0)" ::: "memory");
    __builtin_amdgcn_s_barrier();
    __builtin_amdgcn_sched_barrier(0);
}

#define LROW 128   // bytes per LDS row (64 bf16)
#define SWZ(r) ((((r) >> 2) & 7) << 4)

__global__ __launch_bounds__(256, 2) void k_contract(const float* __restrict__ yv,
                                                     float* __restrict__ outp) {
    __shared__ __align__(16) char lds[5 * 128 * LROW];   // 80KB
    char* A1b = lds;
    char* A2b = lds + 1 * 128 * LROW;
    char* Y0b = lds + 2 * 128 * LROW;
    char* B1b = lds + 3 * 128 * LROW;    // = Y2
    char* B2b = lds + 4 * 128 * LROW;    // = Y1

    const int t  = threadIdx.x;
    const int b  = blockIdx.x >> 5;
    const int xg = blockIdx.x & 31;

    const float* y0p = yv + (size_t)(0 * BNR + b * NN) * AA;
    const float* y1p = yv + (size_t)(1 * BNR + b * NN) * AA;
    const float* y2p = yv + (size_t)(2 * BNR + b * NN) * AA;

    const int lane = t & 63;
    const int wid  = t >> 6;
    const int li   = lane & 31;
    const int rh   = lane >> 5;
    const int rl5  = lane & 31, h2v = lane >> 5;
    const int wy   = wid * 32;            // this wave's output row stripe

    // ---- prologue: prefetch s for all 4 xi (loads BEFORE any store) ----
    float s0v[4], s1v[4], s2v[4];
    #pragma unroll
    for (int xi = 0; xi < 4; ++xi) {
        const int xr = xg * 4 + xi;
        s0v[xi] = y0p[xr * AA + lane];
        s1v[xi] = y1p[xr * AA + lane];
        s2v[xi] = y2p[xr * AA + lane];
    }

    // ---- prologue: stage Y0, B1=Y2, B2=Y1 as bf16 (once per block) ----
    #pragma unroll
    for (int it = 0; it < 16; ++it) {
        const int r   = wid * 32 + it * 2 + rh;
        const int off = r * LROW + ((4 * li) ^ SWZ(r));
        const float2 v0 = *(const float2*)&y0p[r * AA + 2 * li];
        const float2 v1 = *(const float2*)&y1p[r * AA + 2 * li];
        const float2 v2 = *(const float2*)&y2p[r * AA + 2 * li];
        *(unsigned int*)(Y0b + off) = pk2(v0.x, v0.y);
        *(unsigned int*)(B1b + off) = pk2(v2.x, v2.y);
        *(unsigned int*)(B2b + off) = pk2(v1.x, v1.y);
    }

    const float inv = 1.0f / 4096.0f;

    #pragma unroll
    for (int xi = 0; xi < 4; ++xi) {
        const int xr = xg * 4 + xi;
        const float s0a = __shfl(s0v[xi], 2 * li), s0b = __shfl(s0v[xi], 2 * li + 1);
        const float s1a = __shfl(s1v[xi], 2 * li), s1b = __shfl(s1v[xi], 2 * li + 1);
        const float s2a = __shfl(s2v[xi], 2 * li), s2b = __shfl(s2v[xi], 2 * li + 1);

        if (xi == 0) lds_fence_barrier();   // Y panels visible to all waves

        // ---- construct A1/A2 (own rows) from LDS — LGKM ops only ----
        #pragma unroll
        for (int it = 0; it < 16; ++it) {
            const int r   = wid * 32 + it * 2 + rh;
            const int off = r * LROW + ((4 * li) ^ SWZ(r));
            const float2 y0 = unpk(*(const unsigned int*)(Y0b + off));
            const float2 y1 = unpk(*(const unsigned int*)(B2b + off));
            *(unsigned int*)(A1b + off) =
                pk2(s0a * y1.x + s1a * y0.x, s0b * y1.y + s1b * y0.y);
            *(unsigned int*)(A2b + off) = pk2(s2a * y0.x, s2b * y0.y);
        }
        lds_fence_barrier();   // bar1: A staged

        // ---- MFMA, order p0,p1,p2,p3 x ks x ni (bit-identical math) ----
        f32x16 acc[4];
        #pragma unroll
        for (int ni = 0; ni < 4; ++ni)
            #pragma unroll
            for (int e = 0; e < 16; ++e) acc[ni][e] = 0.f;

        #pragma unroll
        for (int p = 0; p < 4; ++p) {
            const char* Ua = (p == 0) ? A1b : (p == 1) ? B1b : (p == 2) ? A2b : B2b;
            const char* Va = (p == 0) ? B1b : (p == 1) ? A1b : (p == 2) ? B2b : A2b;
            #pragma unroll
            for (int ks = 0; ks < 4; ++ks) {
                const int arow = wy + rl5;
                bf16x8 af = *(const bf16x8*)(Ua + arow * LROW +
                              ((ks * 32 + h2v * 16) ^ SWZ(arow)));
                #pragma unroll
                for (int ni = 0; ni < 4; ++ni) {
                    const int brow = 4 * rl5 + ni;      // permuted-B read
                    bf16x8 bf = *(const bf16x8*)(Va + brow * LROW +
                                  ((ks * 32 + h2v * 16) ^ SWZ(brow)));
                    acc[ni] = __builtin_amdgcn_mfma_f32_32x32x16_bf16(
                        af, bf, acc[ni], 0, 0, 0);
                }
            }
        }
        lds_fence_barrier();   // bar2: all A reads done -> next construct safe

        // ---- epilogue: direct full-row stores from registers ----
        // lane rl5 holds problem cols {4rl5..4rl5+3} in acc[0..3][e];
        // row = wy + (e&3) + 8*(e>>2) + 4*h2v. One float4/lane = 512B/half-wave
        // = one full output row. No LDS, no waits; stores drain under next xi.
        float* osl = outp + ((size_t)(b * NN + xr)) * (NN * NN);
        #pragma unroll
        for (int e = 0; e < 16; ++e) {
            const int rowf = wy + (e & 3) + 8 * (e >> 2) + 4 * h2v;
            float4 v = make_float4(acc[0][e] * inv, acc[1][e] * inv,
                                   acc[2][e] * inv, acc[3][e] * inv);
            *(float4*)&osl[(size_t)rowf * NN + 4 * rl5] = v;
        }
    }
}

// ---------------------------------------------------------------------------
extern "C" void kernel_launch(void* const* d_in, const int* in_sizes, int n_in,
                              void* d_out, int out_size, void* d_ws, size_t ws_size,
                              hipStream_t stream) {
    const float* x     = (const float*)d_in[0];
    const float* xmask = (const float*)d_in[1];
    const float* cond  = (const float*)d_in[2];
    const float* cmask = (const float*)d_in[3];
    const float* W1    = (const float*)d_in[4];
    const float* b1    = (const float*)d_in[5];
    const float* Wc    = (const float*)d_in[6];
    const float* Wlin  = (const float*)d_in[7];
    const float* blin  = (const float*)d_in[8];

    float* out = (float*)d_out;
    float* ws  = (float*)d_ws;

    float* dv  = ws;                               // 3*16*256 f
    float* yv  = ws + 12288;                       // 3*2048*64 f
    unsigned short* W1t = (unsigned short*)((char*)d_ws + (size_t)(12288 + 393216) * 4);
    unsigned short* Wlt = W1t + (size_t)DEGN * HH * HH;
    float* dv_out = out + (size_t)BB * NN * NN * NN;

    k_head    <<<dim3(288), dim3(256), 0, stream>>>(cond, cmask, Wc, W1, Wlin,
                                                    dv, dv_out, W1t, Wlt);
    k_mlp     <<<dim3(DEGN * 64), dim3(256), 0, stream>>>(x, xmask, b1, blin, dv,
                                                          W1t, Wlt, yv);
    k_contract<<<dim3(BB * NN / 4), dim3(256), 0, stream>>>(yv, out);
}